// Round 1
// baseline (1987.332 us; speedup 1.0000x reference)
//
#include <hip/hip_runtime.h>
#include <math.h>

#define F_IN   128
#define HID    128
#define NLAYER 3
#define NCLS   40
#define DCAT   512   // F_IN + NLAYER*HID
#define K9     9     // 1 silu + 8 spline bases
#define OPAD   64    // padded out-dim for output layer

// ---------------- device helpers ----------------

static __device__ __forceinline__ float silu_f(float x) {
    return x / (1.f + __expf(-x));
}

// phi = [silu(x), B0..B7] for uniform-knot cubic B-spline grid.
// grid: 12 knots, spacing h, start x0. Valid cells c in [0,10].
static __device__ __forceinline__ void phi9(float x, float x0, float invh, float* v) {
    v[0] = silu_f(x);
#pragma unroll
    for (int j = 1; j < 9; ++j) v[j] = 0.f;
    float t = (x - x0) * invh;
    float cf = floorf(t);
    int c = (int)cf;
    if (cf >= 0.f && c <= 10) {
        float u  = t - cf;
        float um = 1.f - u;
        float u2 = u * u, u3 = u2 * u;
        float w0 = um * um * um * (1.f / 6.f);
        float w1 = (3.f * u3 - 6.f * u2 + 4.f) * (1.f / 6.f);
        float w2 = (-3.f * u3 + 3.f * u2 + 3.f * u + 1.f) * (1.f / 6.f);
        float w3 = u3 * (1.f / 6.f);
        if (c - 3 >= 0)             v[1 + c - 3] = w0;
        if (c - 2 >= 0 && c - 2 < 8) v[1 + c - 2] = w1;
        if (c - 1 >= 0 && c - 1 < 8) v[1 + c - 1] = w2;
        if (c < 8)                   v[1 + c]     = w3;
    }
}

// ---------------- graph preprocessing ----------------

__global__ __launch_bounds__(256) void deg_init_kernel(int* deg, int N) {
    for (int i = blockIdx.x * blockDim.x + threadIdx.x; i < N; i += gridDim.x * blockDim.x)
        deg[i] = 1;  // self-loop
}

__global__ __launch_bounds__(256) void deg_count_kernel(const int* __restrict__ dst, int E, int* deg) {
    for (int i = blockIdx.x * blockDim.x + threadIdx.x; i < E; i += gridDim.x * blockDim.x)
        atomicAdd(&deg[dst[i]], 1);
}

__global__ __launch_bounds__(256) void dinv_kernel(const int* __restrict__ deg, float* dinv, int N) {
    for (int i = blockIdx.x * blockDim.x + threadIdx.x; i < N; i += gridDim.x * blockDim.x)
        dinv[i] = rsqrtf((float)deg[i]);
}

__global__ __launch_bounds__(1024) void scan_kernel(const int* __restrict__ deg, int* offs, int* cursor, int N) {
    __shared__ int part[1024];
    int t = threadIdx.x;
    int chunk = (N + 1023) >> 10;
    int begin = t * chunk;
    int end = begin + chunk; if (end > N) end = N;
    int s = 0;
    for (int i = begin; i < end; ++i) s += deg[i];
    part[t] = s;
    __syncthreads();
    for (int off = 1; off < 1024; off <<= 1) {
        int v = 0;
        if (t >= off) v = part[t - off];
        __syncthreads();
        if (t >= off) part[t] += v;
        __syncthreads();
    }
    int run = (t == 0) ? 0 : part[t - 1];
    for (int i = begin; i < end; ++i) {
        offs[i] = run; cursor[i] = run;
        run += deg[i];
    }
    if (t == 1023) offs[N] = run;
}

__global__ __launch_bounds__(256) void fill_kernel(const int* __restrict__ src, const int* __restrict__ dst,
                                                   int E, int N, int* cursor, int* __restrict__ csr) {
    int total = E + N;
    for (int i = blockIdx.x * blockDim.x + threadIdx.x; i < total; i += gridDim.x * blockDim.x) {
        if (i < E) {
            int d = dst[i];
            int p = atomicAdd(&cursor[d], 1);
            csr[p] = src[i];
        } else {
            int n = i - E;
            int p = atomicAdd(&cursor[n], 1);
            csr[p] = n;
        }
    }
}

// ---------------- weight packing ----------------
// conv pack layout: [l][f][j][o]  (f=input feat, j=0 silu / 1..8 spline, o=out)
__global__ __launch_bounds__(256) void pack_conv_kernel(const float* __restrict__ bw,
                                                        const float* __restrict__ sw,
                                                        const float* __restrict__ sc,
                                                        float* __restrict__ wpk) {
    int total = NLAYER * F_IN * K9 * HID;
    for (int idx = blockIdx.x * blockDim.x + threadIdx.x; idx < total; idx += gridDim.x * blockDim.x) {
        int o = idx % HID;
        int j = (idx / HID) % K9;
        int f = (idx / (HID * K9)) % F_IN;
        int l = idx / (HID * K9 * F_IN);
        int base = (l * HID + o) * F_IN + f;
        float v;
        if (j == 0) v = bw[base];
        else        v = sw[base * 8 + (j - 1)] * sc[base];
        wpk[idx] = v;
    }
}

// out pack layout: [f][j][o] with o padded to OPAD (zeros past NCLS)
__global__ __launch_bounds__(256) void pack_out_kernel(const float* __restrict__ bw,
                                                       const float* __restrict__ sw,
                                                       const float* __restrict__ sc,
                                                       float* __restrict__ wpk) {
    int total = DCAT * K9 * OPAD;
    for (int idx = blockIdx.x * blockDim.x + threadIdx.x; idx < total; idx += gridDim.x * blockDim.x) {
        int o = idx % OPAD;
        int j = (idx / OPAD) % K9;
        int f = idx / (OPAD * K9);
        float v = 0.f;
        if (o < NCLS) {
            int base = o * DCAT + f;
            if (j == 0) v = bw[base];
            else        v = sw[base * 8 + (j - 1)] * sc[base];
        }
        wpk[idx] = v;
    }
}

// ---------------- misc data movement ----------------

__global__ __launch_bounds__(256) void copyx_kernel(const float* __restrict__ x, float* __restrict__ xc, int N) {
    int total = N * F_IN;
    for (int idx = blockIdx.x * blockDim.x + threadIdx.x; idx < total; idx += gridDim.x * blockDim.x) {
        int n = idx >> 7, f = idx & 127;
        xc[(size_t)n * DCAT + f] = x[idx];
    }
}

// ---------------- KAN conv GEMM: 64 nodes x 128 outs per block ----------------
// K = 128 features x 9 phi. Thread tile: 4 nodes x 8 outs.
__global__ __launch_bounds__(256) void kan_conv_kernel(const float* __restrict__ xc, int in_off,
                                                       const float* __restrict__ wpk,
                                                       const float* __restrict__ grid,
                                                       float* __restrict__ hout, int N) {
    __shared__ float phi[8 * K9][64];   // 72 x 64
    __shared__ float wl[8 * K9][HID];   // 72 x 128
    float g0 = grid[0];
    float invh = 1.f / (grid[1] - g0);

    int tid = threadIdx.x;
    int nblk = blockIdx.x * 64;
    int og = tid & 15, ng = tid >> 4;
    int o0 = og * 8, n0 = ng * 4;
    float acc[4][8];
#pragma unroll
    for (int r = 0; r < 4; ++r)
#pragma unroll
        for (int c = 0; c < 8; ++c) acc[r][c] = 0.f;

    for (int fc = 0; fc < F_IN / 8; ++fc) {
        int f0 = fc * 8;
        __syncthreads();
        // stage phi for 64 nodes x 8 features
#pragma unroll
        for (int it = 0; it < 2; ++it) {
            int p = tid + it * 256;
            int node = p & 63, fl = p >> 6;
            int gn = nblk + node;
            float x = (gn < N) ? xc[(size_t)gn * DCAT + in_off + f0 + fl] : 0.f;
            float v[9];
            phi9(x, g0, invh, v);
#pragma unroll
            for (int j = 0; j < 9; ++j) phi[fl * 9 + j][node] = v[j];
        }
        // stage weights: 72*128 floats = 2304 float4
        const float4* wsrc = (const float4*)(wpk + (size_t)f0 * K9 * HID);
        float4* wdst = (float4*)&wl[0][0];
#pragma unroll
        for (int i = 0; i < 9; ++i) wdst[tid + i * 256] = wsrc[tid + i * 256];
        __syncthreads();
#pragma unroll
        for (int k = 0; k < 8 * K9; ++k) {
            float4 a  = *(const float4*)&phi[k][n0];
            float4 b0 = *(const float4*)&wl[k][o0];
            float4 b1 = *(const float4*)&wl[k][o0 + 4];
            float av[4] = {a.x, a.y, a.z, a.w};
            float bv[8] = {b0.x, b0.y, b0.z, b0.w, b1.x, b1.y, b1.z, b1.w};
#pragma unroll
            for (int r = 0; r < 4; ++r)
#pragma unroll
                for (int c = 0; c < 8; ++c)
                    acc[r][c] = fmaf(av[r], bv[c], acc[r][c]);
        }
    }
#pragma unroll
    for (int r = 0; r < 4; ++r) {
        int gn = nblk + n0 + r;
        if (gn < N) {
            float4 v0 = {acc[r][0], acc[r][1], acc[r][2], acc[r][3]};
            float4 v1 = {acc[r][4], acc[r][5], acc[r][6], acc[r][7]};
            *(float4*)&hout[(size_t)gn * HID + o0]     = v0;
            *(float4*)&hout[(size_t)gn * HID + o0 + 4] = v1;
        }
    }
}

// ---------------- output KAN GEMM: 128 nodes x 64(padded 40) outs ----------------
__global__ __launch_bounds__(256) void kan_out_kernel(const float* __restrict__ xc,
                                                      const float* __restrict__ wpk,
                                                      const float* __restrict__ grid,
                                                      float* __restrict__ out, int N) {
    __shared__ float phi[8 * K9][128];  // 72 x 128
    __shared__ float wl[8 * K9][OPAD];  // 72 x 64
    float g0 = grid[0];
    float invh = 1.f / (grid[1] - g0);

    int tid = threadIdx.x;
    int nblk = blockIdx.x * 128;
    int og = tid & 7, ng = tid >> 3;
    int o0 = og * 8, n0 = ng * 4;
    float acc[4][8];
#pragma unroll
    for (int r = 0; r < 4; ++r)
#pragma unroll
        for (int c = 0; c < 8; ++c) acc[r][c] = 0.f;

    for (int fc = 0; fc < DCAT / 8; ++fc) {
        int f0 = fc * 8;
        __syncthreads();
#pragma unroll
        for (int it = 0; it < 4; ++it) {
            int p = tid + it * 256;
            int node = p & 127, fl = p >> 7;
            int gn = nblk + node;
            float x = (gn < N) ? xc[(size_t)gn * DCAT + f0 + fl] : 0.f;
            float v[9];
            phi9(x, g0, invh, v);
#pragma unroll
            for (int j = 0; j < 9; ++j) phi[fl * 9 + j][node] = v[j];
        }
        // stage weights: 72*64 floats = 1152 float4
        {
            const float4* wsrc = (const float4*)(wpk + (size_t)f0 * K9 * OPAD);
            float4* wdst = (float4*)&wl[0][0];
#pragma unroll
            for (int i = 0; i < 5; ++i) {
                int idx = tid + i * 256;
                if (idx < 1152) wdst[idx] = wsrc[idx];
            }
        }
        __syncthreads();
#pragma unroll
        for (int k = 0; k < 8 * K9; ++k) {
            float4 a  = *(const float4*)&phi[k][n0];
            float4 b0 = *(const float4*)&wl[k][o0];
            float4 b1 = *(const float4*)&wl[k][o0 + 4];
            float av[4] = {a.x, a.y, a.z, a.w};
            float bv[8] = {b0.x, b0.y, b0.z, b0.w, b1.x, b1.y, b1.z, b1.w};
#pragma unroll
            for (int r = 0; r < 4; ++r)
#pragma unroll
                for (int c = 0; c < 8; ++c)
                    acc[r][c] = fmaf(av[r], bv[c], acc[r][c]);
        }
    }
    if (o0 < NCLS) {  // og 0..4 cover outs 0..39 exactly
#pragma unroll
        for (int r = 0; r < 4; ++r) {
            int gn = nblk + n0 + r;
            if (gn < N) {
                float4 v0 = {acc[r][0], acc[r][1], acc[r][2], acc[r][3]};
                float4 v1 = {acc[r][4], acc[r][5], acc[r][6], acc[r][7]};
                *(float4*)&out[(size_t)gn * NCLS + o0]     = v0;
                *(float4*)&out[(size_t)gn * NCLS + o0 + 4] = v1;
            }
        }
    }
}

// ---------------- aggregation (one block=128 threads per node) ----------------
__global__ __launch_bounds__(128) void agg_kernel(const float* __restrict__ h,
                                                  const float* __restrict__ dinv,
                                                  const int* __restrict__ offs,
                                                  const int* __restrict__ csr,
                                                  const float* __restrict__ bias,
                                                  float* __restrict__ xc, int out_off, int N) {
    int n = blockIdx.x;
    if (n >= N) return;
    int tid = threadIdx.x;
    int s = offs[n], e = offs[n + 1];
    float acc = 0.f;
    for (int i = s; i < e; ++i) {
        int v = csr[i];
        acc = fmaf(h[(size_t)v * HID + tid], dinv[v], acc);
    }
    xc[(size_t)n * DCAT + out_off + tid] = acc * dinv[n] + bias[tid];
}

// ---------------- batchnorm ----------------
__global__ __launch_bounds__(128) void bn_stats_kernel(const float* __restrict__ xc, int off, int N,
                                                       float* __restrict__ bnsum, float* __restrict__ bnsq) {
    int f = threadIdx.x;
    float s = 0.f, q = 0.f;
    for (int n = blockIdx.x; n < N; n += gridDim.x) {
        float v = xc[(size_t)n * DCAT + off + f];
        s += v;
        q += v * v;
    }
    atomicAdd(&bnsum[f], s);
    atomicAdd(&bnsq[f], q);
}

__global__ __launch_bounds__(256) void bn_apply_kernel(float* xc, int off, int N,
                                                       const float* __restrict__ bnsum,
                                                       const float* __restrict__ bnsq,
                                                       const float* __restrict__ gamma,
                                                       const float* __restrict__ beta) {
    int total = N * HID;
    float invN = 1.f / (float)N;
    for (int idx = blockIdx.x * blockDim.x + threadIdx.x; idx < total; idx += gridDim.x * blockDim.x) {
        int n = idx >> 7, f = idx & 127;
        float mu = bnsum[f] * invN;
        float var = bnsq[f] * invN - mu * mu;
        float rs = rsqrtf(var + 1e-5f);
        size_t a = (size_t)n * DCAT + off + f;
        float v = xc[a];
        xc[a] = (v - mu) * rs * gamma[f] + beta[f];
    }
}

// ---------------- log_softmax (thread per node) ----------------
__global__ __launch_bounds__(256) void logsoftmax_kernel(float* __restrict__ out, int N) {
    for (int n = blockIdx.x * blockDim.x + threadIdx.x; n < N; n += gridDim.x * blockDim.x) {
        float* row = out + (size_t)n * NCLS;
        float m = -1e30f;
#pragma unroll
        for (int j = 0; j < NCLS; ++j) m = fmaxf(m, row[j]);
        float s = 0.f;
#pragma unroll
        for (int j = 0; j < NCLS; ++j) s += __expf(row[j] - m);
        float lse = m + __logf(s);
#pragma unroll
        for (int j = 0; j < NCLS; ++j) row[j] = row[j] - lse;
    }
}

// ---------------- launch ----------------

extern "C" void kernel_launch(void* const* d_in, const int* in_sizes, int n_in,
                              void* d_out, int out_size, void* d_ws, size_t ws_size,
                              hipStream_t stream) {
    const float* x            = (const float*)d_in[0];
    const int*   eidx         = (const int*)d_in[1];
    const float* grid_mp      = (const float*)d_in[2];
    const float* conv_base_w  = (const float*)d_in[3];
    const float* conv_spline_w= (const float*)d_in[4];
    const float* conv_scaler  = (const float*)d_in[5];
    const float* conv_bias    = (const float*)d_in[6];
    const float* bn_gamma     = (const float*)d_in[7];
    const float* bn_beta      = (const float*)d_in[8];
    const float* grid_out     = (const float*)d_in[9];
    const float* out_base_w   = (const float*)d_in[10];
    const float* out_spline_w = (const float*)d_in[11];
    const float* out_scaler   = (const float*)d_in[12];
    float* out = (float*)d_out;

    int N = in_sizes[0] / F_IN;
    int E = in_sizes[1] / 2;
    const int* esrc = eidx;
    const int* edst = eidx + E;

    char* p = (char*)d_ws;
    auto carve = [&](size_t bytes) {
        char* r = p;
        p += (bytes + 255) & ~(size_t)255;
        return r;
    };
    float* xc   = (float*)carve((size_t)N * DCAT * 4);
    float* htmp = (float*)carve((size_t)N * HID * 4);
    float* dinv = (float*)carve((size_t)N * 4);
    float* bn   = (float*)carve((size_t)NLAYER * 2 * HID * 4);
    float* wpkc = (float*)carve((size_t)NLAYER * F_IN * K9 * HID * 4);
    float* wpko = (float*)carve((size_t)DCAT * K9 * OPAD * 4);
    int* deg    = (int*)carve((size_t)N * 4);
    int* offs   = (int*)carve((size_t)(N + 1) * 4);
    int* cursor = (int*)carve((size_t)(N + 1) * 4);
    int* csr    = (int*)carve((size_t)(E + N) * 4);

    hipMemsetAsync(bn, 0, NLAYER * 2 * HID * 4, stream);

    // graph preprocessing
    deg_init_kernel<<<512, 256, 0, stream>>>(deg, N);
    deg_count_kernel<<<1024, 256, 0, stream>>>(edst, E, deg);
    dinv_kernel<<<512, 256, 0, stream>>>(deg, dinv, N);
    scan_kernel<<<1, 1024, 0, stream>>>(deg, offs, cursor, N);
    fill_kernel<<<1024, 256, 0, stream>>>(esrc, edst, E, N, cursor, csr);

    // weight packing + x copy
    pack_conv_kernel<<<1024, 256, 0, stream>>>(conv_base_w, conv_spline_w, conv_scaler, wpkc);
    pack_out_kernel<<<1024, 256, 0, stream>>>(out_base_w, out_spline_w, out_scaler, wpko);
    copyx_kernel<<<2048, 256, 0, stream>>>(x, xc, N);

    int conv_blocks = (N + 63) / 64;
    for (int l = 0; l < NLAYER; ++l) {
        int in_off = l * HID;
        int out_off = (l + 1) * HID;
        const float* wl = wpkc + (size_t)l * F_IN * K9 * HID;
        kan_conv_kernel<<<conv_blocks, 256, 0, stream>>>(xc, in_off, wl, grid_mp, htmp, N);
        agg_kernel<<<N, 128, 0, stream>>>(htmp, dinv, offs, csr, conv_bias + l * HID, xc, out_off, N);
        float* bnsum = bn + l * 2 * HID;
        float* bnsq  = bnsum + HID;
        bn_stats_kernel<<<256, 128, 0, stream>>>(xc, out_off, N, bnsum, bnsq);
        bn_apply_kernel<<<2048, 256, 0, stream>>>(xc, out_off, N, bnsum, bnsq,
                                                  bn_gamma + l * HID, bn_beta + l * HID);
    }

    int out_blocks = (N + 127) / 128;
    kan_out_kernel<<<out_blocks, 256, 0, stream>>>(xc, wpko, grid_out, out, N);
    logsoftmax_kernel<<<(N + 255) / 256, 256, 0, stream>>>(out, N);
}

// Round 2
// 1536.083 us; speedup vs baseline: 1.2938x; 1.2938x over previous
//
#include <hip/hip_runtime.h>
#include <hip/hip_bf16.h>
#include <math.h>

#define F_IN   128
#define HID    128
#define NLAYER 3
#define NCLS   40
#define DCAT   512   // F_IN + NLAYER*HID

typedef short s16x8 __attribute__((ext_vector_type(8)));
typedef unsigned short u16x8 __attribute__((ext_vector_type(8)));
typedef float f32x4 __attribute__((ext_vector_type(4)));

// ---------------- device helpers ----------------

static __device__ __forceinline__ float silu_f(float x) {
    return x / (1.f + __expf(-x));
}

static __device__ __forceinline__ unsigned short f2bf_rn(float f) {
    union { __hip_bfloat16 h; unsigned short u; } cv;
    cv.h = __float2bfloat16(f);
    return cv.u;
}

// ---------------- graph preprocessing ----------------

__global__ __launch_bounds__(256) void deg_init_kernel(int* deg, int N) {
    for (int i = blockIdx.x * blockDim.x + threadIdx.x; i < N; i += gridDim.x * blockDim.x)
        deg[i] = 1;  // self-loop
}

__global__ __launch_bounds__(256) void deg_count_kernel(const int* __restrict__ dst, int E, int* deg) {
    for (int i = blockIdx.x * blockDim.x + threadIdx.x; i < E; i += gridDim.x * blockDim.x)
        atomicAdd(&deg[dst[i]], 1);
}

__global__ __launch_bounds__(256) void dinv_kernel(const int* __restrict__ deg, float* dinv, int N) {
    for (int i = blockIdx.x * blockDim.x + threadIdx.x; i < N; i += gridDim.x * blockDim.x)
        dinv[i] = rsqrtf((float)deg[i]);
}

__global__ __launch_bounds__(1024) void scan_kernel(const int* __restrict__ deg, int* offs, int* cursor, int N) {
    __shared__ int part[1024];
    int t = threadIdx.x;
    int chunk = (N + 1023) >> 10;
    int begin = t * chunk;
    int end = begin + chunk; if (end > N) end = N;
    int s = 0;
    for (int i = begin; i < end; ++i) s += deg[i];
    part[t] = s;
    __syncthreads();
    for (int off = 1; off < 1024; off <<= 1) {
        int v = 0;
        if (t >= off) v = part[t - off];
        __syncthreads();
        if (t >= off) part[t] += v;
        __syncthreads();
    }
    int run = (t == 0) ? 0 : part[t - 1];
    for (int i = begin; i < end; ++i) {
        offs[i] = run; cursor[i] = run;
        run += deg[i];
    }
    if (t == 1023) offs[N] = run;
}

__global__ __launch_bounds__(256) void fill_kernel(const int* __restrict__ src, const int* __restrict__ dst,
                                                   int E, int N, int* cursor, int* __restrict__ csr) {
    int total = E + N;
    for (int i = blockIdx.x * blockDim.x + threadIdx.x; i < total; i += gridDim.x * blockDim.x) {
        if (i < E) {
            int d = dst[i];
            int p = atomicAdd(&cursor[d], 1);
            csr[p] = src[i];
        } else {
            int n = i - E;
            int p = atomicAdd(&cursor[n], 1);
            csr[p] = n;
        }
    }
}

// ---------------- weight packing (bf16, pre-swizzled [chunk][o][k^((o&7)<<3)]) -------

__global__ __launch_bounds__(256) void pack_conv_mfma(const float* __restrict__ bw,
                                                      const float* __restrict__ sw,
                                                      const float* __restrict__ sc,
                                                      unsigned short* __restrict__ wpk) {
    int total = NLAYER * 9 * 128 * 128;
    for (int idx = blockIdx.x * blockDim.x + threadIdx.x; idx < total; idx += gridDim.x * blockDim.x) {
        int k = idx & 127;
        int o = (idx >> 7) & 127;
        int j = (idx >> 14) % 9;
        int l = idx / (9 << 14);
        int base = (l * 128 + o) * 128 + k;   // bw[l][o][f=k]
        float v;
        if (j == 0) v = bw[base];
        else        v = sw[base * 8 + (j - 1)] * sc[base];
        int dst = ((l * 9 + j) * 128 + o) * 128 + (k ^ ((o & 7) << 3));
        wpk[dst] = f2bf_rn(v);
    }
}

__global__ __launch_bounds__(256) void pack_out_mfma(const float* __restrict__ bw,
                                                     const float* __restrict__ sw,
                                                     const float* __restrict__ sc,
                                                     unsigned short* __restrict__ wpk) {
    int total = 36 * 64 * 128;
    for (int idx = blockIdx.x * blockDim.x + threadIdx.x; idx < total; idx += gridDim.x * blockDim.x) {
        int k = idx & 127;
        int o = (idx >> 7) & 63;
        int cc = idx >> 13;      // 0..35
        int j = cc >> 2;
        int fb = cc & 3;
        int f = fb * 128 + k;
        float v = 0.f;
        if (o < NCLS) {
            int base = o * DCAT + f;
            if (j == 0) v = bw[base];
            else        v = sw[base * 8 + (j - 1)] * sc[base];
        }
        int dst = (cc * 64 + o) * 128 + (k ^ ((o & 7) << 3));
        wpk[dst] = f2bf_rn(v);
    }
}

// ---------------- misc data movement ----------------

__global__ __launch_bounds__(256) void copyx_kernel(const float* __restrict__ x, float* __restrict__ xc, int N) {
    int total = N * F_IN;
    for (int idx = blockIdx.x * blockDim.x + threadIdx.x; idx < total; idx += gridDim.x * blockDim.x) {
        int n = idx >> 7, f = idx & 127;
        xc[(size_t)n * DCAT + f] = x[idx];
    }
}

__global__ __launch_bounds__(512) void affine_init_kernel(float* scA, float* shA) {
    int i = threadIdx.x;
    scA[i] = 1.f; shA[i] = 0.f;
}

// ---------------- fused KAN GEMM (bf16 MFMA 16x16x32) ----------------
// Block: 256 threads (4 waves 2x2), tile 128 nodes x OUTT outs.
// K chunked: NCH chunks of 128 (j-major; FBLKS feature-blocks per j).
// phi computed on the fly into swizzled LDS; W pre-swizzled in global, linear-staged.
template<int OUTT, int FBLKS, int NCH, bool MASK40>
__global__ __launch_bounds__(256, 2) void kan_mfma_kernel(
    const float* __restrict__ xc, int in_off,
    const float* __restrict__ scA, const float* __restrict__ shA,
    const unsigned short* __restrict__ wpk,
    const float* __restrict__ grid,
    float* __restrict__ outp, int out_ld, int N) {

    constexpr int CT = OUTT / 32;          // col frag tiles per wave
    constexpr int WITERS = OUTT / 16;      // float4 staging iters for W
    __shared__ __align__(16) char lds[32768 + OUTT * 256];
    char* lds_phi = lds;
    char* lds_w = lds + 32768;

    const int tid = threadIdx.x;
    const int lane = tid & 63;
    const int wave = tid >> 6;
    const int wr = wave >> 1, wc = wave & 1;
    const int l15 = lane & 15, lg = lane >> 4;
    const int nblk = blockIdx.x * 128;

    const float g0 = grid[0];
    const float invh = 1.f / (grid[1] - g0);

    // staging decomposition: thread handles 8 nodes x 8 features
    const int fgrp = tid & 15;            // feature group (8 f)
    const int ngrp = tid >> 4;            // node group (8 n)
    const int f0 = fgrp * 8;

    f32x4 acc[4][CT];
#pragma unroll
    for (int r = 0; r < 4; ++r)
#pragma unroll
        for (int c = 0; c < CT; ++c) acc[r][c] = (f32x4)0.f;

    for (int cc = 0; cc < NCH; ++cc) {
        const int j = (FBLKS == 1) ? cc : (cc >> 2);
        const int fb = (FBLKS == 1) ? 0 : (cc & 3);

        // issue W staging loads (global -> regs) before the barrier
        const float4* wg = (const float4*)(wpk + (size_t)cc * OUTT * 128);
        float4 wreg[WITERS];
#pragma unroll
        for (int i = 0; i < WITERS; ++i) wreg[i] = wg[tid + i * 256];

        // per-thread affine params for its 8 features
        const int abase = in_off + fb * 128 + f0;
        float4 sc0 = *(const float4*)(scA + abase);
        float4 sc1 = *(const float4*)(scA + abase + 4);
        float4 sh0 = *(const float4*)(shA + abase);
        float4 sh1 = *(const float4*)(shA + abase + 4);
        float scv[8] = {sc0.x, sc0.y, sc0.z, sc0.w, sc1.x, sc1.y, sc1.z, sc1.w};
        float shv[8] = {sh0.x, sh0.y, sh0.z, sh0.w, sh1.x, sh1.y, sh1.z, sh1.w};

        __syncthreads();   // previous chunk's MFMA reads complete

        // phi staging: 8 nodes x 8 features per thread
        for (int i = 0; i < 8; ++i) {
            int n_loc = ngrp * 8 + i;
            int gn = nblk + n_loc;
            float xv[8];
            if (gn < N) {
                const float* xrow = xc + (size_t)gn * DCAT + in_off + fb * 128 + f0;
                float4 a = *(const float4*)xrow;
                float4 b = *(const float4*)(xrow + 4);
                xv[0]=a.x; xv[1]=a.y; xv[2]=a.z; xv[3]=a.w;
                xv[4]=b.x; xv[5]=b.y; xv[6]=b.z; xv[7]=b.w;
            } else {
#pragma unroll
                for (int e = 0; e < 8; ++e) xv[e] = 0.f;
            }
            u16x8 pv;
#pragma unroll
            for (int e = 0; e < 8; ++e) {
                float y = fmaf(xv[e], scv[e], shv[e]);
                float v;
                if (j == 0) {
                    v = silu_f(y);
                } else {
                    float t = (y - g0) * invh;
                    float cf = floorf(t);
                    float u = t - cf;
                    int d = (int)cf - (j - 1);
                    float um = 1.f - u;
                    float u2 = u * u;
                    float w0 = um * um * um * (1.f / 6.f);
                    float w3 = u * u2 * (1.f / 6.f);
                    float w1 = fmaf(fmaf(0.5f, u, -1.f), u2, 2.f / 3.f);
                    float w2 = fmaf(fmaf(-0.5f, u, 0.5f), u2, fmaf(0.5f, u, 1.f / 6.f));
                    v = (d == 0) ? w3 : (d == 1) ? w2 : (d == 2) ? w1 : (d == 3) ? w0 : 0.f;
                }
                pv[e] = f2bf_rn(v);
            }
            int byte = n_loc * 256 + ((f0 * 2) ^ ((n_loc & 7) << 4));
            *(u16x8*)(lds_phi + byte) = pv;
        }

        // write W regs -> LDS (linear)
        float4* wl = (float4*)lds_w;
#pragma unroll
        for (int i = 0; i < WITERS; ++i) wl[tid + i * 256] = wreg[i];

        __syncthreads();

        // MFMA over 4 k-steps of 32
#pragma unroll
        for (int s = 0; s < 4; ++s) {
            const int kslot = (s * 4 + lg) * 16;
            s16x8 af[4];
#pragma unroll
            for (int r = 0; r < 4; ++r) {
                int n = wr * 64 + r * 16 + l15;
                int byte = n * 256 + (kslot ^ ((n & 7) << 4));
                af[r] = *(const s16x8*)(lds_phi + byte);
            }
#pragma unroll
            for (int c = 0; c < CT; ++c) {
                int o = wc * (OUTT / 2) + c * 16 + l15;
                int byte = o * 256 + (kslot ^ ((o & 7) << 4));
                s16x8 bfr = *(const s16x8*)(lds_w + byte);
#pragma unroll
                for (int r = 0; r < 4; ++r)
                    acc[r][c] = __builtin_amdgcn_mfma_f32_16x16x32_bf16(af[r], bfr, acc[r][c], 0, 0, 0);
            }
        }
    }

    // epilogue: C row=node (lg*4+q within 16-tile), col=out (l15)
#pragma unroll
    for (int r = 0; r < 4; ++r) {
        int nb = nblk + wr * 64 + r * 16 + lg * 4;
#pragma unroll
        for (int c = 0; c < CT; ++c) {
            int o = wc * (OUTT / 2) + c * 16 + l15;
            if (!MASK40 || o < NCLS) {
#pragma unroll
                for (int q = 0; q < 4; ++q) {
                    int n = nb + q;
                    if (n < N) outp[(size_t)n * out_ld + o] = acc[r][c][q];
                }
            }
        }
    }
}

// ---------------- aggregation (one block=128 threads per node) ----------------
__global__ __launch_bounds__(128) void agg_kernel(const float* __restrict__ h,
                                                  const float* __restrict__ dinv,
                                                  const int* __restrict__ offs,
                                                  const int* __restrict__ csr,
                                                  const float* __restrict__ bias,
                                                  float* __restrict__ xc, int out_off, int N) {
    int n = blockIdx.x;
    if (n >= N) return;
    int tid = threadIdx.x;
    int s = offs[n], e = offs[n + 1];
    float acc = 0.f;
    for (int i = s; i < e; ++i) {
        int v = csr[i];
        acc = fmaf(h[(size_t)v * HID + tid], dinv[v], acc);
    }
    xc[(size_t)n * DCAT + out_off + tid] = acc * dinv[n] + bias[tid];
}

// ---------------- batchnorm stats + deferred affine ----------------
__global__ __launch_bounds__(128) void bn_stats_kernel(const float* __restrict__ xc, int off, int N,
                                                       float* __restrict__ bnsum, float* __restrict__ bnsq) {
    int f = threadIdx.x;
    float s = 0.f, q = 0.f;
    for (int n = blockIdx.x; n < N; n += gridDim.x) {
        float v = xc[(size_t)n * DCAT + off + f];
        s += v;
        q += v * v;
    }
    atomicAdd(&bnsum[f], s);
    atomicAdd(&bnsq[f], q);
}

__global__ __launch_bounds__(128) void bn_affine_kernel(const float* __restrict__ bnsum,
                                                        const float* __restrict__ bnsq,
                                                        const float* __restrict__ gamma,
                                                        const float* __restrict__ beta,
                                                        float* scA, float* shA, int seg_off, float invN) {
    int f = threadIdx.x;
    float mu = bnsum[f] * invN;
    float var = bnsq[f] * invN - mu * mu;
    float rs = rsqrtf(var + 1e-5f);
    float s = gamma[f] * rs;
    scA[seg_off + f] = s;
    shA[seg_off + f] = fmaf(-mu, s, beta[f]);
}

// ---------------- log_softmax (thread per node) ----------------
__global__ __launch_bounds__(256) void logsoftmax_kernel(float* __restrict__ out, int N) {
    for (int n = blockIdx.x * blockDim.x + threadIdx.x; n < N; n += gridDim.x * blockDim.x) {
        float* row = out + (size_t)n * NCLS;
        float m = -1e30f;
#pragma unroll
        for (int j = 0; j < NCLS; ++j) m = fmaxf(m, row[j]);
        float s = 0.f;
#pragma unroll
        for (int j = 0; j < NCLS; ++j) s += __expf(row[j] - m);
        float lse = m + __logf(s);
#pragma unroll
        for (int j = 0; j < NCLS; ++j) row[j] = row[j] - lse;
    }
}

// ---------------- launch ----------------

extern "C" void kernel_launch(void* const* d_in, const int* in_sizes, int n_in,
                              void* d_out, int out_size, void* d_ws, size_t ws_size,
                              hipStream_t stream) {
    const float* x            = (const float*)d_in[0];
    const int*   eidx         = (const int*)d_in[1];
    const float* grid_mp      = (const float*)d_in[2];
    const float* conv_base_w  = (const float*)d_in[3];
    const float* conv_spline_w= (const float*)d_in[4];
    const float* conv_scaler  = (const float*)d_in[5];
    const float* conv_bias    = (const float*)d_in[6];
    const float* bn_gamma     = (const float*)d_in[7];
    const float* bn_beta      = (const float*)d_in[8];
    const float* grid_out     = (const float*)d_in[9];
    const float* out_base_w   = (const float*)d_in[10];
    const float* out_spline_w = (const float*)d_in[11];
    const float* out_scaler   = (const float*)d_in[12];
    float* out = (float*)d_out;

    int N = in_sizes[0] / F_IN;
    int E = in_sizes[1] / 2;
    const int* esrc = eidx;
    const int* edst = eidx + E;

    char* p = (char*)d_ws;
    auto carve = [&](size_t bytes) {
        char* r = p;
        p += (bytes + 255) & ~(size_t)255;
        return r;
    };
    float* xc   = (float*)carve((size_t)N * DCAT * 4);
    float* htmp = (float*)carve((size_t)N * HID * 4);
    float* dinv = (float*)carve((size_t)N * 4);
    float* bn   = (float*)carve((size_t)NLAYER * 2 * HID * 4);
    float* scA  = (float*)carve((size_t)DCAT * 4);
    float* shA  = (float*)carve((size_t)DCAT * 4);
    unsigned short* wpkc = (unsigned short*)carve((size_t)NLAYER * 9 * 128 * 128 * 2);
    unsigned short* wpko = (unsigned short*)carve((size_t)36 * 64 * 128 * 2);
    int* deg    = (int*)carve((size_t)N * 4);
    int* offs   = (int*)carve((size_t)(N + 1) * 4);
    int* cursor = (int*)carve((size_t)(N + 1) * 4);
    int* csr    = (int*)carve((size_t)(E + N) * 4);

    hipMemsetAsync(bn, 0, NLAYER * 2 * HID * 4, stream);

    // graph preprocessing
    deg_init_kernel<<<512, 256, 0, stream>>>(deg, N);
    deg_count_kernel<<<1024, 256, 0, stream>>>(edst, E, deg);
    dinv_kernel<<<512, 256, 0, stream>>>(deg, dinv, N);
    scan_kernel<<<1, 1024, 0, stream>>>(deg, offs, cursor, N);
    fill_kernel<<<1024, 256, 0, stream>>>(esrc, edst, E, N, cursor, csr);

    // weight packing + x copy + affine init
    pack_conv_mfma<<<1024, 256, 0, stream>>>(conv_base_w, conv_spline_w, conv_scaler, wpkc);
    pack_out_mfma<<<1024, 256, 0, stream>>>(out_base_w, out_spline_w, out_scaler, wpko);
    copyx_kernel<<<2048, 256, 0, stream>>>(x, xc, N);
    affine_init_kernel<<<1, 512, 0, stream>>>(scA, shA);

    int blocks = (N + 127) / 128;
    float invN = 1.f / (float)N;
    for (int l = 0; l < NLAYER; ++l) {
        int in_off = l * HID;
        int out_off = (l + 1) * HID;
        const unsigned short* wl = wpkc + (size_t)l * 9 * 128 * 128;
        kan_mfma_kernel<128, 1, 9, false><<<blocks, 256, 0, stream>>>(
            xc, in_off, scA, shA, wl, grid_mp, htmp, HID, N);
        agg_kernel<<<N, 128, 0, stream>>>(htmp, dinv, offs, csr, conv_bias + l * HID, xc, out_off, N);
        float* bnsum = bn + l * 2 * HID;
        float* bnsq  = bnsum + HID;
        bn_stats_kernel<<<256, 128, 0, stream>>>(xc, out_off, N, bnsum, bnsq);
        bn_affine_kernel<<<1, 128, 0, stream>>>(bnsum, bnsq, bn_gamma + l * HID, bn_beta + l * HID,
                                                scA, shA, out_off, invN);
    }

    kan_mfma_kernel<64, 4, 36, true><<<blocks, 256, 0, stream>>>(
        xc, 0, scA, shA, wpko, grid_out, out, NCLS, N);
    logsoftmax_kernel<<<(N + 255) / 256, 256, 0, stream>>>(out, N);
}

// Round 3
// 882.819 us; speedup vs baseline: 2.2511x; 1.7400x over previous
//
#include <hip/hip_runtime.h>
#include <hip/hip_bf16.h>
#include <math.h>

#define F_IN   128
#define HID    128
#define NLAYER 3
#define NCLS   40
#define DCAT   512   // F_IN + NLAYER*HID
#define KSL    10    // slots per feature: silu, B0..B7, pad
#define FCH    16    // features per K-chunk
#define KCH    (FCH * KSL)   // 160 K-elems per chunk
#define ROWB   (KCH * 2)     // 320 bytes per LDS row

typedef short s16x8 __attribute__((ext_vector_type(8)));
typedef unsigned short u16x8 __attribute__((ext_vector_type(8)));
typedef float f32x4 __attribute__((ext_vector_type(4)));

// ---------------- device helpers ----------------

static __device__ __forceinline__ float silu_f(float x) {
    return x / (1.f + __expf(-x));
}

static __device__ __forceinline__ unsigned short f2bf_rn(float f) {
    union { __hip_bfloat16 h; unsigned short u; } cv;
    cv.h = __float2bfloat16(f);
    return cv.u;
}

// ---------------- graph preprocessing ----------------

__global__ __launch_bounds__(256) void deg_init_kernel(int* deg, int N) {
    for (int i = blockIdx.x * blockDim.x + threadIdx.x; i < N; i += gridDim.x * blockDim.x)
        deg[i] = 1;  // self-loop
}

__global__ __launch_bounds__(256) void deg_count_kernel(const int* __restrict__ dst, int E, int* deg) {
    for (int i = blockIdx.x * blockDim.x + threadIdx.x; i < E; i += gridDim.x * blockDim.x)
        atomicAdd(&deg[dst[i]], 1);
}

__global__ __launch_bounds__(256) void dinv_kernel(const int* __restrict__ deg, float* dinv, int N) {
    for (int i = blockIdx.x * blockDim.x + threadIdx.x; i < N; i += gridDim.x * blockDim.x)
        dinv[i] = rsqrtf((float)deg[i]);
}

__global__ __launch_bounds__(1024) void scan_kernel(const int* __restrict__ deg, int* offs, int* cursor, int N) {
    __shared__ int part[1024];
    int t = threadIdx.x;
    int chunk = (N + 1023) >> 10;
    int begin = t * chunk;
    int end = begin + chunk; if (end > N) end = N;
    int s = 0;
    for (int i = begin; i < end; ++i) s += deg[i];
    part[t] = s;
    __syncthreads();
    for (int off = 1; off < 1024; off <<= 1) {
        int v = 0;
        if (t >= off) v = part[t - off];
        __syncthreads();
        if (t >= off) part[t] += v;
        __syncthreads();
    }
    int run = (t == 0) ? 0 : part[t - 1];
    for (int i = begin; i < end; ++i) {
        offs[i] = run; cursor[i] = run;
        run += deg[i];
    }
    if (t == 1023) offs[N] = run;
}

__global__ __launch_bounds__(256) void fill_kernel(const int* __restrict__ src, const int* __restrict__ dst,
                                                   int E, int N, int* cursor, int* __restrict__ csr) {
    int total = E + N;
    for (int i = blockIdx.x * blockDim.x + threadIdx.x; i < total; i += gridDim.x * blockDim.x) {
        if (i < E) {
            int d = dst[i];
            int p = atomicAdd(&cursor[d], 1);
            csr[p] = src[i];
        } else {
            int n = i - E;
            int p = atomicAdd(&cursor[n], 1);
            csr[p] = n;
        }
    }
}

// ---------------- weight packing (bf16, K = [feature][10 slots]) -------------
// conv layout: [l][cc(8)][o(128)][fl(16)*10 + j]
__global__ __launch_bounds__(256) void pack_conv_mfma(const float* __restrict__ bw,
                                                      const float* __restrict__ sw,
                                                      const float* __restrict__ sc,
                                                      unsigned short* __restrict__ wpk) {
    int total = NLAYER * 8 * 128 * KCH;
    for (int idx = blockIdx.x * blockDim.x + threadIdx.x; idx < total; idx += gridDim.x * blockDim.x) {
        int e  = idx % KCH;
        int fl = e / KSL;
        int j  = e % KSL;
        int o  = (idx / KCH) & 127;
        int cc = (idx / (KCH * 128)) & 7;
        int l  = idx / (KCH * 128 * 8);
        int f = cc * FCH + fl;
        int base = (l * 128 + o) * 128 + f;
        float v;
        if (j == 0)      v = bw[base];
        else if (j <= 8) v = sw[base * 8 + (j - 1)] * sc[base];
        else             v = 0.f;
        wpk[idx] = f2bf_rn(v);
    }
}

// out layout: [cc(32)][o(64)][fl*10 + j], o >= NCLS zeroed
__global__ __launch_bounds__(256) void pack_out_mfma(const float* __restrict__ bw,
                                                     const float* __restrict__ sw,
                                                     const float* __restrict__ sc,
                                                     unsigned short* __restrict__ wpk) {
    int total = 32 * 64 * KCH;
    for (int idx = blockIdx.x * blockDim.x + threadIdx.x; idx < total; idx += gridDim.x * blockDim.x) {
        int e  = idx % KCH;
        int fl = e / KSL;
        int j  = e % KSL;
        int o  = (idx / KCH) & 63;
        int cc = idx / (KCH * 64);
        int f = cc * FCH + fl;
        float v = 0.f;
        if (o < NCLS && j <= 8) {
            int base = o * DCAT + f;
            if (j == 0) v = bw[base];
            else        v = sw[base * 8 + (j - 1)] * sc[base];
        }
        wpk[idx] = f2bf_rn(v);
    }
}

// ---------------- misc data movement ----------------

__global__ __launch_bounds__(256) void copyx_kernel(const float* __restrict__ x, float* __restrict__ xc, int N) {
    int total = N * F_IN;
    for (int idx = blockIdx.x * blockDim.x + threadIdx.x; idx < total; idx += gridDim.x * blockDim.x) {
        int n = idx >> 7, f = idx & 127;
        xc[(size_t)n * DCAT + f] = x[idx];
    }
}

__global__ __launch_bounds__(512) void affine_init_kernel(float* scA, float* shA) {
    int i = threadIdx.x;
    scA[i] = 1.f; shA[i] = 0.f;
}

// ---------------- fused KAN GEMM (bf16 MFMA 16x16x32, f-major K) -------------
// Block: 256 threads (4 waves 2x2), tile 128 nodes x OUTT outs.
// NCH chunks of 16 features (K=160 each, incl zero-pad slot).
// phi computed once per (n,f) into LDS (320B rows -> natural bank stagger).
template<int OUTT, int NCH, bool MASK40>
__global__ __launch_bounds__(256, 2) void kan_mfma_kernel(
    const float* __restrict__ xc, int in_off,
    const float* __restrict__ scA, const float* __restrict__ shA,
    const unsigned short* __restrict__ wpk,
    const float* __restrict__ grid,
    float* __restrict__ outp, int out_ld, int N) {

    constexpr int CT = OUTT / 32;          // col frag tiles per wave
    constexpr int WITERS = OUTT * ROWB / 16 / 256;  // float4 staging iters for W
    __shared__ __align__(16) char lds[128 * ROWB + OUTT * ROWB];
    char* lds_phi = lds;
    char* lds_w = lds + 128 * ROWB;

    const int tid = threadIdx.x;
    const int lane = tid & 63;
    const int wave = tid >> 6;
    const int wr = wave >> 1, wc = wave & 1;
    const int l15 = lane & 15, lg = lane >> 4;
    const int nblk = blockIdx.x * 128;

    const float g0 = grid[0];
    const float invh = 1.f / (grid[1] - g0);

    // staging decomposition: thread -> (fg = tid&3 : 4 features), nodes {n0, n0+64}
    const int fg = tid & 3;
    const int n0 = tid >> 2;          // 0..63

    f32x4 acc[4][CT];
#pragma unroll
    for (int r = 0; r < 4; ++r)
#pragma unroll
        for (int c = 0; c < CT; ++c) acc[r][c] = (f32x4)0.f;

    // prefetch chunk 0: x rows + affine
    float4 xv[2], xn[2], scv, shv, scn, shn;
    {
        const int abase = in_off + fg * 4;
        scv = *(const float4*)(scA + abase);
        shv = *(const float4*)(shA + abase);
        int gn0 = nblk + n0, gn1 = nblk + n0 + 64;
        const float* r0 = xc + (size_t)gn0 * DCAT + in_off + fg * 4;
        const float* r1 = xc + (size_t)gn1 * DCAT + in_off + fg * 4;
        xv[0] = (gn0 < N) ? *(const float4*)r0 : (float4){0.f, 0.f, 0.f, 0.f};
        xv[1] = (gn1 < N) ? *(const float4*)r1 : (float4){0.f, 0.f, 0.f, 0.f};
    }

    for (int cc = 0; cc < NCH; ++cc) {
        // issue W staging loads (global -> regs)
        const float4* wg = (const float4*)(wpk + (size_t)cc * OUTT * KCH);
        float4 wreg[WITERS];
#pragma unroll
        for (int i = 0; i < WITERS; ++i) wreg[i] = wg[tid + i * 256];

        // prefetch next chunk's x + affine
        if (cc + 1 < NCH) {
            const int abase = in_off + (cc + 1) * FCH + fg * 4;
            scn = *(const float4*)(scA + abase);
            shn = *(const float4*)(shA + abase);
            int gn0 = nblk + n0, gn1 = nblk + n0 + 64;
            const float* r0 = xc + (size_t)gn0 * DCAT + abase;
            const float* r1 = xc + (size_t)gn1 * DCAT + abase;
            xn[0] = (gn0 < N) ? *(const float4*)r0 : (float4){0.f, 0.f, 0.f, 0.f};
            xn[1] = (gn1 < N) ? *(const float4*)r1 : (float4){0.f, 0.f, 0.f, 0.f};
        }

        // compute phi for 2 nodes x 4 features -> 2 x 5 u16x8
        u16x8 pv[2][5];
#pragma unroll
        for (int g = 0; g < 2; ++g) {
            float xin[4] = {xv[g].x, xv[g].y, xv[g].z, xv[g].w};
            float scr[4] = {scv.x, scv.y, scv.z, scv.w};
            float shr[4] = {shv.x, shv.y, shv.z, shv.w};
            float ph[4][KSL];
#pragma unroll
            for (int fl = 0; fl < 4; ++fl) {
                float y = fmaf(xin[fl], scr[fl], shr[fl]);
                ph[fl][0] = silu_f(y);
                float t = (y - g0) * invh;
                float cf = floorf(t);
                int c = (int)cf;
                float u = t - cf;
                float um = 1.f - u;
                float u2 = u * u;
                float um2 = um * um;
                float w0 = um2 * um * (1.f / 6.f);
                float w3 = u2 * u * (1.f / 6.f);
                float w1 = fmaf(fmaf(0.5f, u, -1.f), u2, 2.f / 3.f);
                float w2 = fmaf(fmaf(-0.5f, u, 0.5f), u2, fmaf(0.5f, u, 1.f / 6.f));
                bool e[11];
#pragma unroll
                for (int v = 0; v < 11; ++v) e[v] = (c == v);
#pragma unroll
                for (int s = 0; s < 8; ++s) {
                    float val = 0.f;
                    val = e[s] ? w3 : val;
                    if (s + 1 <= 10) val = e[s + 1] ? w2 : val;
                    if (s + 2 <= 10) val = e[s + 2] ? w1 : val;
                    if (s + 3 <= 10) val = e[s + 3] ? w0 : val;
                    ph[fl][1 + s] = val;
                }
                ph[fl][9] = 0.f;
            }
#pragma unroll
            for (int k = 0; k < 5; ++k) {
#pragma unroll
                for (int el = 0; el < 8; ++el) {
                    int sidx = k * 8 + el;
                    pv[g][k][el] = f2bf_rn(ph[sidx / KSL][sidx % KSL]);
                }
            }
        }

        __syncthreads();   // previous chunk's MFMA reads complete

        // write phi (2 nodes x 80B) + W (linear copy) to LDS
        {
            char* p0 = lds_phi + n0 * ROWB + fg * 80;
            char* p1 = lds_phi + (n0 + 64) * ROWB + fg * 80;
#pragma unroll
            for (int k = 0; k < 5; ++k) {
                *(u16x8*)(p0 + k * 16) = pv[0][k];
                *(u16x8*)(p1 + k * 16) = pv[1][k];
            }
            float4* wl = (float4*)lds_w;
#pragma unroll
            for (int i = 0; i < WITERS; ++i) wl[tid + i * 256] = wreg[i];
        }

        __syncthreads();

        // MFMA over 5 k-steps of 32
#pragma unroll
        for (int kk = 0; kk < 5; ++kk) {
            const int kb = kk * 64 + lg * 16;
            s16x8 af[4];
#pragma unroll
            for (int r = 0; r < 4; ++r) {
                int n = wr * 64 + r * 16 + l15;
                af[r] = *(const s16x8*)(lds_phi + n * ROWB + kb);
            }
#pragma unroll
            for (int c = 0; c < CT; ++c) {
                int o = wc * (OUTT / 2) + c * 16 + l15;
                s16x8 bfr = *(const s16x8*)(lds_w + o * ROWB + kb);
#pragma unroll
                for (int r = 0; r < 4; ++r)
                    acc[r][c] = __builtin_amdgcn_mfma_f32_16x16x32_bf16(af[r], bfr, acc[r][c], 0, 0, 0);
            }
        }

        xv[0] = xn[0]; xv[1] = xn[1];
        scv = scn; shv = shn;
    }

    // epilogue: C row=node (lg*4+q within 16-tile), col=out (l15)
#pragma unroll
    for (int r = 0; r < 4; ++r) {
        int nb = nblk + wr * 64 + r * 16 + lg * 4;
#pragma unroll
        for (int c = 0; c < CT; ++c) {
            int o = wc * (OUTT / 2) + c * 16 + l15;
            if (!MASK40 || o < NCLS) {
#pragma unroll
                for (int q = 0; q < 4; ++q) {
                    int n = nb + q;
                    if (n < N) outp[(size_t)n * out_ld + o] = acc[r][c][q];
                }
            }
        }
    }
}

// ---------------- aggregation (one wave per node, float2 lanes) --------------
__global__ __launch_bounds__(256) void agg_kernel(const float* __restrict__ h,
                                                  const float* __restrict__ dinv,
                                                  const int* __restrict__ offs,
                                                  const int* __restrict__ csr,
                                                  const float* __restrict__ bias,
                                                  float* __restrict__ xc, int out_off, int N) {
    int n = blockIdx.x * 4 + (threadIdx.x >> 6);
    if (n >= N) return;
    int lane = threadIdx.x & 63;
    int s = offs[n], e = offs[n + 1];
    float a0 = 0.f, a1 = 0.f;
    for (int i = s; i < e; ++i) {
        int v = csr[i];
        float dv = dinv[v];
        float2 hv = *(const float2*)(h + (size_t)v * HID + lane * 2);
        a0 = fmaf(hv.x, dv, a0);
        a1 = fmaf(hv.y, dv, a1);
    }
    float dn = dinv[n];
    float2 bv = *(const float2*)(bias + lane * 2);
    float2 res = {a0 * dn + bv.x, a1 * dn + bv.y};
    *(float2*)(xc + (size_t)n * DCAT + out_off + lane * 2) = res;
}

// ---------------- batchnorm stats + deferred affine ----------------
__global__ __launch_bounds__(128) void bn_stats_kernel(const float* __restrict__ xc, int off, int N,
                                                       float* __restrict__ bnsum, float* __restrict__ bnsq) {
    int f = threadIdx.x;
    float s = 0.f, q = 0.f;
    for (int n = blockIdx.x; n < N; n += gridDim.x) {
        float v = xc[(size_t)n * DCAT + off + f];
        s += v;
        q += v * v;
    }
    atomicAdd(&bnsum[f], s);
    atomicAdd(&bnsq[f], q);
}

__global__ __launch_bounds__(128) void bn_affine_kernel(const float* __restrict__ bnsum,
                                                        const float* __restrict__ bnsq,
                                                        const float* __restrict__ gamma,
                                                        const float* __restrict__ beta,
                                                        float* scA, float* shA, int seg_off, float invN) {
    int f = threadIdx.x;
    float mu = bnsum[f] * invN;
    float var = bnsq[f] * invN - mu * mu;
    float rs = rsqrtf(var + 1e-5f);
    float s = gamma[f] * rs;
    scA[seg_off + f] = s;
    shA[seg_off + f] = fmaf(-mu, s, beta[f]);
}

// ---------------- log_softmax (thread per node) ----------------
__global__ __launch_bounds__(256) void logsoftmax_kernel(float* __restrict__ out, int N) {
    for (int n = blockIdx.x * blockDim.x + threadIdx.x; n < N; n += gridDim.x * blockDim.x) {
        float* row = out + (size_t)n * NCLS;
        float m = -1e30f;
#pragma unroll
        for (int j = 0; j < NCLS; ++j) m = fmaxf(m, row[j]);
        float s = 0.f;
#pragma unroll
        for (int j = 0; j < NCLS; ++j) s += __expf(row[j] - m);
        float lse = m + __logf(s);
#pragma unroll
        for (int j = 0; j < NCLS; ++j) row[j] = row[j] - lse;
    }
}

// ---------------- launch ----------------

extern "C" void kernel_launch(void* const* d_in, const int* in_sizes, int n_in,
                              void* d_out, int out_size, void* d_ws, size_t ws_size,
                              hipStream_t stream) {
    const float* x            = (const float*)d_in[0];
    const int*   eidx         = (const int*)d_in[1];
    const float* grid_mp      = (const float*)d_in[2];
    const float* conv_base_w  = (const float*)d_in[3];
    const float* conv_spline_w= (const float*)d_in[4];
    const float* conv_scaler  = (const float*)d_in[5];
    const float* conv_bias    = (const float*)d_in[6];
    const float* bn_gamma     = (const float*)d_in[7];
    const float* bn_beta      = (const float*)d_in[8];
    const float* grid_out     = (const float*)d_in[9];
    const float* out_base_w   = (const float*)d_in[10];
    const float* out_spline_w = (const float*)d_in[11];
    const float* out_scaler   = (const float*)d_in[12];
    float* out = (float*)d_out;

    int N = in_sizes[0] / F_IN;
    int E = in_sizes[1] / 2;
    const int* esrc = eidx;
    const int* edst = eidx + E;

    char* p = (char*)d_ws;
    auto carve = [&](size_t bytes) {
        char* r = p;
        p += (bytes + 255) & ~(size_t)255;
        return r;
    };
    float* xc   = (float*)carve((size_t)N * DCAT * 4);
    float* htmp = (float*)carve((size_t)N * HID * 4);
    float* dinv = (float*)carve((size_t)N * 4);
    float* bn   = (float*)carve((size_t)NLAYER * 2 * HID * 4);
    float* scA  = (float*)carve((size_t)DCAT * 4);
    float* shA  = (float*)carve((size_t)DCAT * 4);
    unsigned short* wpkc = (unsigned short*)carve((size_t)NLAYER * 8 * 128 * KCH * 2);
    unsigned short* wpko = (unsigned short*)carve((size_t)32 * 64 * KCH * 2);
    int* deg    = (int*)carve((size_t)N * 4);
    int* offs   = (int*)carve((size_t)(N + 1) * 4);
    int* cursor = (int*)carve((size_t)(N + 1) * 4);
    int* csr    = (int*)carve((size_t)(E + N) * 4);

    hipMemsetAsync(bn, 0, NLAYER * 2 * HID * 4, stream);

    // graph preprocessing
    deg_init_kernel<<<512, 256, 0, stream>>>(deg, N);
    deg_count_kernel<<<1024, 256, 0, stream>>>(edst, E, deg);
    dinv_kernel<<<512, 256, 0, stream>>>(deg, dinv, N);
    scan_kernel<<<1, 1024, 0, stream>>>(deg, offs, cursor, N);
    fill_kernel<<<1024, 256, 0, stream>>>(esrc, edst, E, N, cursor, csr);

    // weight packing + x copy + affine init
    pack_conv_mfma<<<1024, 256, 0, stream>>>(conv_base_w, conv_spline_w, conv_scaler, wpkc);
    pack_out_mfma<<<1024, 256, 0, stream>>>(out_base_w, out_spline_w, out_scaler, wpko);
    copyx_kernel<<<2048, 256, 0, stream>>>(x, xc, N);
    affine_init_kernel<<<1, 512, 0, stream>>>(scA, shA);

    int blocks = (N + 127) / 128;
    float invN = 1.f / (float)N;
    for (int l = 0; l < NLAYER; ++l) {
        int in_off = l * HID;
        int out_off = (l + 1) * HID;
        const unsigned short* wl = wpkc + (size_t)l * 8 * 128 * KCH;
        kan_mfma_kernel<128, 8, false><<<blocks, 256, 0, stream>>>(
            xc, in_off, scA, shA, wl, grid_mp, htmp, HID, N);
        agg_kernel<<<(N + 3) / 4, 256, 0, stream>>>(htmp, dinv, offs, csr, conv_bias + l * HID, xc, out_off, N);
        float* bnsum = bn + l * 2 * HID;
        float* bnsq  = bnsum + HID;
        bn_stats_kernel<<<256, 128, 0, stream>>>(xc, out_off, N, bnsum, bnsq);
        bn_affine_kernel<<<1, 128, 0, stream>>>(bnsum, bnsq, bn_gamma + l * HID, bn_beta + l * HID,
                                                scA, shA, out_off, invN);
    }

    kan_mfma_kernel<64, 32, true><<<blocks, 256, 0, stream>>>(
        xc, 0, scA, shA, wpko, grid_out, out, NCLS, N);
    logsoftmax_kernel<<<(N + 255) / 256, 256, 0, stream>>>(out, N);
}